// Round 6
// baseline (249.673 us; speedup 1.0000x reference)
//
#include <hip/hip_runtime.h>

#define C_IN   672
#define C_OUT  128
#define HW     49
#define XELEMS (C_IN*HW)      // 32928
#define NKS    21             // 672 / 32 k-steps

typedef short  short8 __attribute__((ext_vector_type(8)));
typedef float  f4     __attribute__((ext_vector_type(4)));

__device__ __forceinline__ unsigned short f2bf(float f) {
    unsigned u = __float_as_uint(f);
    u += 0x7fffu + ((u >> 16) & 1u);
    return (unsigned short)(u >> 16);
}

__global__ __launch_bounds__(256) void prep_kernel(
        const float* __restrict__ gamma,
        const float* __restrict__ beta,
        const float* __restrict__ rmean,
        const float* __restrict__ rvar,
        const float* __restrict__ W,
        unsigned short* __restrict__ Wbf,
        float* __restrict__ scale,
        float* __restrict__ shift) {
    int i = blockIdx.x * 256 + threadIdx.x;
    if (i < C_IN) {
        float inv = rsqrtf(rvar[i] + 1e-5f);
        float sc  = gamma[i] * inv;
        scale[i] = sc;
        shift[i] = beta[i] - rmean[i] * sc;
    }
    if (i < C_OUT * C_IN) Wbf[i] = f2bf(W[i]);
}

// out_b(128x49) = W(128x672) @ relu(x_b*scale+shift)(672x49), one block per b,
// wave wv owns m-strip [wv*32, wv*32+32).
// R6: NO LDS, NO BARRIERS. R1/R4/R5 all plateaued at 71-74 us: the 2-barrier
// chunk protocol phase-locks all resident blocks (every vmcnt(0) drain stalls
// the whole CU). x is L3/L2-hot (R3 FETCH=66MB < 135MB of x), so each wave
// builds B-fragments directly from global: lane(quad,l16) loads
// x[ks*32+quad*8+j][nt*16+l16] (4x64B segments/instr, fully used), applies
// BN+ReLU, packs bf16. 21 independent k-steps pipeline freely.
__global__ __launch_bounds__(256) void gemm_kernel(
        const float* __restrict__ x,
        const unsigned short* __restrict__ Wbf,
        const float* __restrict__ scale,
        const float* __restrict__ shift,
        float* __restrict__ out) {
    const int tid  = threadIdx.x;
    const int b    = blockIdx.x;
    const int wv   = tid >> 6;        // wave -> m-strip of 32 rows
    const int lane = tid & 63;
    const int quad = lane >> 4;
    const int l16  = lane & 15;

    const float* xb = x + (size_t)b * XELEMS;

    // per-lane spatial column for each n-tile; nt=3 clamps to s=48 (only
    // scol=48 is stored; clamped lanes compute garbage-but-finite, masked out)
    int col[4];
    #pragma unroll
    for (int nt = 0; nt < 4; ++nt) {
        int s = nt * 16 + l16;
        col[nt] = (s < HW) ? s : (HW - 1);
    }

    f4 acc[2][4];
    #pragma unroll
    for (int mt = 0; mt < 2; ++mt)
        #pragma unroll
        for (int nt = 0; nt < 4; ++nt)
            acc[mt][nt] = (f4){0.f, 0.f, 0.f, 0.f};

    for (int ks = 0; ks < NKS; ++ks) {
        const int kbase = ks * 32 + quad * 8;   // 8 channels this lane covers

        // BN params for the 8 channels (16B vector loads, broadcast per quad)
        f4 sc0 = *(const f4*)(scale + kbase);
        f4 sc1 = *(const f4*)(scale + kbase + 4);
        f4 sh0 = *(const f4*)(shift + kbase);
        f4 sh1 = *(const f4*)(shift + kbase + 4);

        // A-fragments from L2-resident bf16 W
        short8 av[2];
        #pragma unroll
        for (int mt = 0; mt < 2; ++mt) {
            int row = wv * 32 + mt * 16 + l16;
            av[mt] = *(const short8*)(Wbf + row * C_IN + ks * 32 + quad * 8);
        }

        // B-fragments straight from global x: 8 loads per nt, BN+ReLU+pack
        const float* xk = xb + kbase * HW;
        short8 bv[4];
        #pragma unroll
        for (int nt = 0; nt < 4; ++nt) {
            float v[8];
            #pragma unroll
            for (int j = 0; j < 8; ++j)
                v[j] = xk[j * HW + col[nt]];
            #pragma unroll
            for (int j = 0; j < 8; ++j) {
                float s = (j < 4) ? sc0[j] : sc1[j - 4];
                float h = (j < 4) ? sh0[j] : sh1[j - 4];
                bv[nt][j] = (short)f2bf(fmaxf(v[j] * s + h, 0.f));
            }
        }

        #pragma unroll
        for (int mt = 0; mt < 2; ++mt)
            #pragma unroll
            for (int nt = 0; nt < 4; ++nt)
                acc[mt][nt] = __builtin_amdgcn_mfma_f32_16x16x32_bf16(
                    av[mt], bv[nt], acc[mt][nt], 0, 0, 0);
    }

    // epilogue: C/D layout col=lane&15, row=quad*4+reg (m89-verified); mask s>=49
    float* outb = out + (size_t)b * (C_OUT * HW);
    #pragma unroll
    for (int mt = 0; mt < 2; ++mt) {
        #pragma unroll
        for (int nt = 0; nt < 4; ++nt) {
            int scol = nt * 16 + l16;
            if (scol < HW) {
                #pragma unroll
                for (int i = 0; i < 4; ++i) {
                    int o = wv * 32 + mt * 16 + quad * 4 + i;
                    outb[o * HW + scol] = acc[mt][nt][i];
                }
            }
        }
    }
}

extern "C" void kernel_launch(void* const* d_in, const int* in_sizes, int n_in,
                              void* d_out, int out_size, void* d_ws, size_t ws_size,
                              hipStream_t stream) {
    const float* x     = (const float*)d_in[0];
    const float* gamma = (const float*)d_in[1];
    const float* beta  = (const float*)d_in[2];
    const float* rmean = (const float*)d_in[3];
    const float* rvar  = (const float*)d_in[4];
    const float* W     = (const float*)d_in[5];
    float* out = (float*)d_out;

    // ws layout: [bf16 W: 86016*2 B][scale: 672 f32][shift: 672 f32]  (~173 KB)
    unsigned short* Wbf = (unsigned short*)d_ws;
    float* scale = (float*)((char*)d_ws + (size_t)C_OUT * C_IN * 2);
    float* shift = scale + C_IN;

    prep_kernel<<<(C_OUT * C_IN + 255) / 256, 256, 0, stream>>>(
        gamma, beta, rmean, rvar, W, Wbf, scale, shift);
    gemm_kernel<<<1024, 256, 0, stream>>>(x, Wbf, scale, shift, out);
}